// Round 1
// 73.832 us; speedup vs baseline: 1.0127x; 1.0127x over previous
//
#include <hip/hip_runtime.h>

// Problem constants
#define BB 8
#define CIN 16
#define COUT 64
#define HH 32
#define WW 32
#define PH 34
#define PW 34
#define PPLANE (PH * PW) // 1156

// denom = 2*N_EKV*VT = 0.075. Everything pre-scaled into log2-units:
//   xp = x * C,  th' = clip(theta,1,8) * C,  C = log2(e)/0.075
//   b1 = xp - th' = (x-theta)*C;  b2 = b1 - 0.1*C
// Reference clip(a,-50,20) == post-log l = min(log2(1+2^b), B_HI) (fp32-exact:
// b >= B_HI -> log2(1+2^b)==b; b <= -30 -> 1+2^b rounds to 1 -> l=0).
// d >= 1.6: both l's hit B_HI -> cancel exactly (matches reference's clip).
// d <= -0.72 (b1 <= -13.85): f < 5e-9 -> skip via wave-uniform branch.
#define SCALE_C 19.235933878519388f /* (1/0.075)*log2(e) */
#define K2V (SCALE_C * 0.1f)        /* b2 = b1 - K2V */
#define B_HI 28.85390081777927f     /* 20*log2e */
#define WINLO_S (-13.849872392533959f) /* -0.72 * SCALE_C */
// final scale: ln2^2 * ALPHA * R (times runtime `scale`)
#define OUT_CONST (0.4804530139182014f * 0.05625f * 0.1f)

#define EXP2F(x) __builtin_amdgcn_exp2f(x)
#define LOG2F(x) __builtin_amdgcn_logf(x)

// f-LUT: the whole per-tap nonlinearity is single-variable in b1:
//   f(b1) = min(log2(1+2^b1),B_HI)^2 - min(log2(1+2^(b1-K2V)),B_HI)^2
// tabulated at b1 = (i - 234)*TAB_H, i = 0..746, TAB_H = SCALE_C/320.
// Knot alignment (exact by construction, no fp fuzz):
//   u(B_HI)      = 20 *320*0.075 + 234 = 714  (saturation knee of l1... l2)
//   u(B_HI+K2V)  = (64/3)*320*0.075 + 234 = 746  (f reaches exactly 0)
// so both slope-kinks sit ON knots -> piecewise-linear interp has zero
// kink error; the linear mid-region [~15,28.85] is reproduced exactly.
// Curved region (b1 in (-14,15)): |f''| <~ 5, lerp err <= 5*h^2/8 ~ 2e-3.
// Below index 0 / above 746: clamp; T ~ 0 at both ends (6e-9 / exact 0).
// Inactive lanes (b1 < WINLO_S) clamp to u=0 -> LDS same-address broadcast.
#define TAB_H (SCALE_C / 320.0f)
#define TAB_INVH (320.0f / SCALE_C)
#define TAB_OFF 234.0f
#define TAB_UMAX 746.5f
#define TAB_LAST 746
#define TAB_N 752 /* 746 real + T[747..751]=0 pad for the i+1 read */

#define NTH (COUT * CIN * 9) // 9216

// blocks 0..577: pad+prescale x into xp ([8][16][34][34]);
// blocks 578..613: prescale clipped theta (9216 elems).
__global__ __launch_bounds__(256) void init_kernel(const float* __restrict__ x,
                                                   const float* __restrict__ theta,
                                                   float* __restrict__ xp,
                                                   float* __restrict__ thp) {
    if (blockIdx.x < 578) {
        int idx = blockIdx.x * 256 + threadIdx.x; // 578*256 = 147968 exactly
        int c = idx / PPLANE;
        int r = idx - c * PPLANE;
        int y = r / PW;
        int xc = r - y * PW;
        float v = 0.0f;
        if (y >= 1 && y <= HH && xc >= 1 && xc <= WW) {
            v = x[c * (HH * WW) + (y - 1) * WW + (xc - 1)] * SCALE_C;
        }
        xp[idx] = v;
    } else {
        int i = (blockIdx.x - 578) * 256 + threadIdx.x;
        if (i < NTH) {
            thp[i] = fminf(fmaxf(theta[i], 1.0f), 8.0f) * SCALE_C;
        }
    }
}

__device__ __forceinline__ void load9(const float* __restrict__ p, float* v) {
#pragma unroll
    for (int dy = 0; dy < 3; ++dy)
#pragma unroll
        for (int dx = 0; dx < 3; ++dx)
            v[dy * 3 + dx] = p[dy * PW + dx];
}

// thp indices are block-uniform -> s_load; sub/cmp use the SGPR operand.
// Untaken tap: v_sub + v_cmp + s_cbranch. Taken tap: clamp + lerp from the
// LDS f-table — no transcendentals, no long dependence chain.
__device__ __forceinline__ void compute9(const float* v, const float* __restrict__ thp,
                                         const float* __restrict__ T, float* acc) {
#pragma unroll
    for (int k = 0; k < 9; ++k) {
        float b1 = v[k] - thp[k];
        if (__any(b1 > WINLO_S)) {
            float u = fmaf(b1, TAB_INVH, TAB_OFF);
            u = fminf(fmaxf(u, 0.0f), TAB_UMAX); // v_med3; clamped lanes broadcast
            float fi = floorf(u);
            float fr = u - fi;
            int i = (int)fi;
            float t0 = T[i];
            float t1 = T[i + 1]; // ds_read2_b32 with t0
            float a = acc[k % 3];
            a += fmaf(fr, t1 - t0, t0);
            acc[k % 3] = a;
        }
    }
}

// Block mapping chosen for the MI355X round-robin dispatch (bid%8 -> XCD,
// then sequential fill within XCD: CU c of XCD j hosts bids j+8c+256m,
// m=0..7). Decode so those 8 co-resident blocks share the SAME (b,tile)
// 26KB x-slice (L1-resident; ~1.4KB hot plane in lockstep) and differ only
// in co (bits 8..10 -> cm):
//   b = bid&7 (== XCD id), tile = (bid>>3)&3, co = (bid>>8)*8 + ((bid>>5)&7)
// Per-XCD L2 then holds just one 74KB batch slice of xp.
__global__ __launch_bounds__(256, 8) void ekv_kernel(const float* __restrict__ xp,
                                                     const float* __restrict__ thp,
                                                     const float* __restrict__ scale,
                                                     float* __restrict__ out) {
    __shared__ float T[TAB_N];
    // Build the f-table once per block: ~3 entries/thread, transcendentals
    // live ONLY here (752 evals/block vs ~22M in the old inner loop).
    for (int i = threadIdx.x; i < TAB_N; i += 256) {
        float val = 0.0f;
        if (i <= TAB_LAST) {
            float b1 = ((float)i - TAB_OFF) * TAB_H;
            float e1 = EXP2F(b1);
            float l1 = fminf(LOG2F(1.0f + e1), B_HI);
            float e2 = EXP2F(b1 - K2V);
            float l2 = fminf(LOG2F(1.0f + e2), B_HI);
            val = fmaf(l1, l1, -(l2 * l2));
        }
        T[i] = val;
    }
    __syncthreads();

    int bid = blockIdx.x;
    int b = bid & 7;
    int tile = (bid >> 3) & 3;
    int cl = (bid >> 5) & 7;
    int cm = bid >> 8;
    int co = cm * 8 + cl;

    int t = threadIdx.x;
    int ow = t & 31;
    int oh = tile * 8 + (t >> 5);

    const float* thc = thp + co * (CIN * 9);
    const float* p0 = xp + (size_t)b * (CIN * PPLANE) + oh * PW + ow;

    float acc[3] = {0.0f, 0.0f, 0.0f};

    // Register ping-pong over cin: prefetch next plane's 9 taps while current
    // plane's 9 evals run.
    float va[9], vb[9];
    load9(p0, va);
#pragma unroll 1
    for (int cin = 0; cin < CIN; cin += 2) {
        load9(p0 + (cin + 1) * PPLANE, vb);
        compute9(va, thc + cin * 9, T, acc);
        int nc = cin + 2 < CIN ? cin + 2 : CIN - 1; // clamp: harmless re-read
        load9(p0 + nc * PPLANE, va);
        compute9(vb, thc + (cin + 1) * 9, T, acc);
    }

    float sc = scale[0] * (OUT_CONST);
    out[(((size_t)b * COUT + co) * HH + oh) * WW + ow] =
        (acc[0] + acc[1] + acc[2]) * sc;
}

extern "C" void kernel_launch(void* const* d_in, const int* in_sizes, int n_in,
                              void* d_out, int out_size, void* d_ws, size_t ws_size,
                              hipStream_t stream) {
    const float* x = (const float*)d_in[0];
    const float* theta = (const float*)d_in[1];
    const float* scale = (const float*)d_in[2];
    float* out = (float*)d_out;

    // ws layout: [0, 36KB) prescaled theta (9216 f32); then padded x (147968 f32)
    float* thp = (float*)d_ws;
    float* xp = thp + NTH;
    (void)ws_size;

    init_kernel<<<578 + (NTH + 255) / 256, 256, 0, stream>>>(x, theta, xp, thp);
    ekv_kernel<<<BB * 4 * COUT, 256, 0, stream>>>(xp, thp, scale, out);
}